// Round 9
// baseline (3132.405 us; speedup 1.0000x reference)
//
#include <hip/hip_runtime.h>
#include <cstddef>

#define HQ 2048
#define NKVH 4
#define HDIM 128
#define QKV_N 3072
#define ATT_SCALE 0.08838834764831845f
#define KSPLIT 16
#define CHUNK 64
#define NCH 64

__device__ __forceinline__ float4 f4max(float4 a, float4 b) {
  return make_float4(fmaxf(a.x, b.x), fmaxf(a.y, b.y), fmaxf(a.z, b.z), fmaxf(a.w, b.w));
}

// ---------------------------------------------------------------------------
// Projection / reduce: unchanged from R6.
// ---------------------------------------------------------------------------
template <int N>
__global__ __launch_bounds__(256) void proj_kernel(const float* __restrict__ X,
                                                   const float* __restrict__ W,
                                                   float* __restrict__ part) {
  __shared__ union {
    float x[32][128];
    float red[32][4][64];
  } sm;
  const int t = threadIdx.x;
  const int c0 = blockIdx.x << 6;
  const int ksb = blockIdx.y;
  const int k0 = ksb << 7;
  const int c = t & 63;
  const int ksub = t >> 6;

#pragma unroll
  for (int i = 0; i < 4; ++i) {
    const int id = t + (i << 8);
    const int bb = id >> 5, kk = (id & 31) << 2;
    *reinterpret_cast<float4*>(&sm.x[bb][kk]) =
        *reinterpret_cast<const float4*>(X + bb * HQ + k0 + kk);
  }
  __syncthreads();

  float acc[32];
#pragma unroll
  for (int b = 0; b < 32; ++b) acc[b] = 0.f;

#pragma unroll
  for (int kk4 = 0; kk4 < 8; ++kk4) {
    const int kk = (ksub << 5) + (kk4 << 2);
    const float* wp = W + (size_t)(k0 + kk) * N + c0 + c;
    const float w0 = wp[0];
    const float w1 = wp[N];
    const float w2 = wp[2 * N];
    const float w3 = wp[3 * N];
#pragma unroll
    for (int b = 0; b < 32; ++b) {
      const float4 x4 = *reinterpret_cast<const float4*>(&sm.x[b][kk]);
      acc[b] = fmaf(x4.x, w0, acc[b]);
      acc[b] = fmaf(x4.y, w1, acc[b]);
      acc[b] = fmaf(x4.z, w2, acc[b]);
      acc[b] = fmaf(x4.w, w3, acc[b]);
    }
  }
  __syncthreads();
#pragma unroll
  for (int b = 0; b < 32; ++b) sm.red[b][ksub][c] = acc[b];
  __syncthreads();
#pragma unroll
  for (int i = 0; i < 8; ++i) {
    const int o = t + (i << 8);
    const int b = o >> 6, cc = o & 63;
    const float v = sm.red[b][0][cc] + sm.red[b][1][cc] + sm.red[b][2][cc] + sm.red[b][3][cc];
    part[(size_t)(ksb * 32 + b) * N + c0 + cc] = v;
  }
}

template <int NCOL, bool HAS_BIAS>
__global__ __launch_bounds__(256) void reduce_kernel(const float* __restrict__ part,
                                                     const float* __restrict__ bias,
                                                     float* __restrict__ out) {
  const int o = blockIdx.x * 256 + threadIdx.x;
  constexpr int total = 32 * NCOL;
  float s = 0.f;
#pragma unroll
  for (int ks = 0; ks < KSPLIT; ++ks) s += part[(size_t)ks * total + o];
  if (HAS_BIAS) s += bias[o % NCOL];
  out[o] = s;
}

// ---------------------------------------------------------------------------
// Attention kernel: R6 verbatim (best-known-good structure).
// ---------------------------------------------------------------------------
__global__ __launch_bounds__(256, 4) void attn_kernel(const float* __restrict__ cache,
                                                      const int* __restrict__ seq_lens,
                                                      const int* __restrict__ slot_map,
                                                      const float* __restrict__ qkv,
                                                      float* __restrict__ ml,
                                                      float* __restrict__ accp) {
  __shared__ float pt[4][16][4];
  __shared__ float pvbuf[4][128][4];
  __shared__ float redm[4][4];
  __shared__ float redl[4][4];

  const int t = threadIdx.x;
  const int bid = blockIdx.x;
  const int chunk = bid & 63;
  const int kvh = (bid >> 6) & 3;
  const int b = bid >> 8;
  const int L = seq_lens[b];
  const int start = chunk << 6;
  if (start >= L) return;
  const int n = min(CHUNK, L - start);
  const int send = start + n;
  const int slot = slot_map[b];
  const float* __restrict__ qrow = qkv + b * QKV_N;
  const float* __restrict__ knew = qrow + 2048 + (kvh << 7);
  const float* __restrict__ vnew = qrow + 2560 + (kvh << 7);

  const int w = t >> 6, l = t & 63;
  const int l16 = l & 15, rq = l >> 4;
  const int wbase = w << 4;

  auto krow_ptr = [&](int r) -> const float* {
    int sg = start + r;
    sg = (sg < send) ? sg : start;
    return (sg == slot) ? knew : cache + (((size_t)((b << 12) + sg)) << 10) + (kvh << 7);
  };
  auto vrow_ptr = [&](int r) -> const float* {
    int sg = start + r;
    sg = (sg < send) ? sg : start;
    return (sg == slot) ? vnew : cache + (((size_t)((b << 12) + sg)) << 10) + 512 + (kvh << 7);
  };

  float4 qr[4][2];
#pragma unroll
  for (int g = 0; g < 4; ++g) {
#pragma unroll
    for (int e = 0; e < 2; ++e)
      qr[g][e] = *reinterpret_cast<const float4*>(qrow + ((kvh << 2) + g) * HDIM +
                                                  (l16 << 3) + (e << 2));
  }
  float4 ka[8];
#pragma unroll
  for (int rg = 0; rg < 4; ++rg) {
    const float* kp = krow_ptr(wbase + (rg << 2) + rq) + (l16 << 3);
    ka[2 * rg] = *reinterpret_cast<const float4*>(kp);
    ka[2 * rg + 1] = *reinterpret_cast<const float4*>(kp + 4);
  }
  float2 va[16];
#pragma unroll
  for (int s = 0; s < 16; ++s)
    va[s] = *reinterpret_cast<const float2*>(vrow_ptr(wbase + s) + (l << 1));

  float4 m4 = make_float4(-1e30f, -1e30f, -1e30f, -1e30f);
  float4 scr[4];
#pragma unroll
  for (int rg = 0; rg < 4; ++rg) {
    const float4 k0 = ka[2 * rg], k1 = ka[2 * rg + 1];
    float s0 = fmaf(k0.x, qr[0][0].x, fmaf(k0.y, qr[0][0].y, fmaf(k0.z, qr[0][0].z, k0.w * qr[0][0].w)));
    s0 = fmaf(k1.x, qr[0][1].x, fmaf(k1.y, qr[0][1].y, fmaf(k1.z, qr[0][1].z, fmaf(k1.w, qr[0][1].w, s0))));
    float s1 = fmaf(k0.x, qr[1][0].x, fmaf(k0.y, qr[1][0].y, fmaf(k0.z, qr[1][0].z, k0.w * qr[1][0].w)));
    s1 = fmaf(k1.x, qr[1][1].x, fmaf(k1.y, qr[1][1].y, fmaf(k1.z, qr[1][1].z, fmaf(k1.w, qr[1][1].w, s1))));
    float s2 = fmaf(k0.x, qr[2][0].x, fmaf(k0.y, qr[2][0].y, fmaf(k0.z, qr[2][0].z, k0.w * qr[2][0].w)));
    s2 = fmaf(k1.x, qr[2][1].x, fmaf(k1.y, qr[2][1].y, fmaf(k1.z, qr[2][1].z, fmaf(k1.w, qr[2][1].w, s2))));
    float s3 = fmaf(k0.x, qr[3][0].x, fmaf(k0.y, qr[3][0].y, fmaf(k0.z, qr[3][0].z, k0.w * qr[3][0].w)));
    s3 = fmaf(k1.x, qr[3][1].x, fmaf(k1.y, qr[3][1].y, fmaf(k1.z, qr[3][1].z, fmaf(k1.w, qr[3][1].w, s3))));
#pragma unroll
    for (int off = 1; off <= 8; off <<= 1) {
      s0 += __shfl_xor(s0, off);
      s1 += __shfl_xor(s1, off);
      s2 += __shfl_xor(s2, off);
      s3 += __shfl_xor(s3, off);
    }
    scr[rg] = make_float4(s0 * ATT_SCALE, s1 * ATT_SCALE, s2 * ATT_SCALE, s3 * ATT_SCALE);
    if (wbase + (rg << 2) + rq < n) m4 = f4max(m4, scr[rg]);
  }

  m4.x = fmaxf(m4.x, __shfl_xor(m4.x, 16));
  m4.y = fmaxf(m4.y, __shfl_xor(m4.y, 16));
  m4.z = fmaxf(m4.z, __shfl_xor(m4.z, 16));
  m4.w = fmaxf(m4.w, __shfl_xor(m4.w, 16));
  m4.x = fmaxf(m4.x, __shfl_xor(m4.x, 32));
  m4.y = fmaxf(m4.y, __shfl_xor(m4.y, 32));
  m4.z = fmaxf(m4.z, __shfl_xor(m4.z, 32));
  m4.w = fmaxf(m4.w, __shfl_xor(m4.w, 32));
  if (l == 0) *reinterpret_cast<float4*>(&redm[w][0]) = m4;
  __syncthreads();
  float4 M4 = *reinterpret_cast<const float4*>(&redm[0][0]);
  M4 = f4max(M4, *reinterpret_cast<const float4*>(&redm[1][0]));
  M4 = f4max(M4, *reinterpret_cast<const float4*>(&redm[2][0]));
  M4 = f4max(M4, *reinterpret_cast<const float4*>(&redm[3][0]));

  float4 lsum = make_float4(0.f, 0.f, 0.f, 0.f);
#pragma unroll
  for (int rg = 0; rg < 4; ++rg) {
    const int row = wbase + (rg << 2) + rq;
    float4 e = make_float4(0.f, 0.f, 0.f, 0.f);
    if (row < n) {
      e.x = __expf(scr[rg].x - M4.x);
      e.y = __expf(scr[rg].y - M4.y);
      e.z = __expf(scr[rg].z - M4.z);
      e.w = __expf(scr[rg].w - M4.w);
    }
    lsum.x += e.x; lsum.y += e.y; lsum.z += e.z; lsum.w += e.w;
    if (l16 == 0) *reinterpret_cast<float4*>(&pt[w][(rg << 2) + rq][0]) = e;
  }
  lsum.x += __shfl_xor(lsum.x, 16); lsum.y += __shfl_xor(lsum.y, 16);
  lsum.z += __shfl_xor(lsum.z, 16); lsum.w += __shfl_xor(lsum.w, 16);
  lsum.x += __shfl_xor(lsum.x, 32); lsum.y += __shfl_xor(lsum.y, 32);
  lsum.z += __shfl_xor(lsum.z, 32); lsum.w += __shfl_xor(lsum.w, 32);
  if (l == 0) *reinterpret_cast<float4*>(&redl[w][0]) = lsum;
  asm volatile("s_waitcnt lgkmcnt(0)" ::: "memory");

  float4 accA = make_float4(0.f, 0.f, 0.f, 0.f);
  float4 accB = make_float4(0.f, 0.f, 0.f, 0.f);
#pragma unroll
  for (int s = 0; s < 16; ++s) {
    const float4 p = *reinterpret_cast<const float4*>(&pt[w][s][0]);
    const float2 vv = va[s];
    accA.x = fmaf(p.x, vv.x, accA.x); accA.y = fmaf(p.y, vv.x, accA.y);
    accA.z = fmaf(p.z, vv.x, accA.z); accA.w = fmaf(p.w, vv.x, accA.w);
    accB.x = fmaf(p.x, vv.y, accB.x); accB.y = fmaf(p.y, vv.y, accB.y);
    accB.z = fmaf(p.z, vv.y, accB.z); accB.w = fmaf(p.w, vv.y, accB.w);
  }

  *reinterpret_cast<float4*>(&pvbuf[w][l << 1][0]) = accA;
  *reinterpret_cast<float4*>(&pvbuf[w][(l << 1) + 1][0]) = accB;
  __syncthreads();

  if (t < 128) {
    const int d = t;
    float4 s0 = *reinterpret_cast<const float4*>(&pvbuf[0][d][0]);
    const float4 s1 = *reinterpret_cast<const float4*>(&pvbuf[1][d][0]);
    const float4 s2 = *reinterpret_cast<const float4*>(&pvbuf[2][d][0]);
    const float4 s3 = *reinterpret_cast<const float4*>(&pvbuf[3][d][0]);
    s0.x += s1.x + s2.x + s3.x;
    s0.y += s1.y + s2.y + s3.y;
    s0.z += s1.z + s2.z + s3.z;
    s0.w += s1.w + s2.w + s3.w;
    float* ap = accp + (size_t)bid * 512;
    ap[d] = s0.x;
    ap[128 + d] = s0.y;
    ap[256 + d] = s0.z;
    ap[384 + d] = s0.w;
  }
  if (t == 0) {
    float4 Lt = *reinterpret_cast<const float4*>(&redl[0][0]);
    const float4 l1 = *reinterpret_cast<const float4*>(&redl[1][0]);
    const float4 l2 = *reinterpret_cast<const float4*>(&redl[2][0]);
    const float4 l3 = *reinterpret_cast<const float4*>(&redl[3][0]);
    Lt.x += l1.x + l2.x + l3.x;
    Lt.y += l1.y + l2.y + l3.y;
    Lt.z += l1.z + l2.z + l3.z;
    Lt.w += l1.w + l2.w + l3.w;
    *reinterpret_cast<float4*>(ml + (size_t)bid * 8) = M4;
    *reinterpret_cast<float4*>(ml + (size_t)bid * 8 + 4) = Lt;
  }
}

__global__ __launch_bounds__(128) void combine_kernel(const int* __restrict__ seq_lens,
                                                      const float* __restrict__ ml,
                                                      const float* __restrict__ accp,
                                                      float* __restrict__ attn) {
  const int blk = blockIdx.x;
  const int g = blk & 3, kvh = (blk >> 2) & 3, b = blk >> 4;
  const int d = threadIdx.x;
  const int L = seq_lens[b];
  const int nch = (L + CHUNK - 1) >> 6;
  const int base = (b * 4 + kvh) * NCH;

  float M = -1e30f;
  for (int c = 0; c < nch; ++c) M = fmaxf(M, ml[(size_t)(base + c) * 8 + g]);
  float osum = 0.f, lsum = 0.f;
  for (int c = 0; c < nch; ++c) {
    const int idx = base + c;
    const float mc = ml[(size_t)idx * 8 + g];
    const float lc = ml[(size_t)idx * 8 + 4 + g];
    const float wgt = __expf(mc - M);
    lsum = fmaf(lc, wgt, lsum);
    osum = fmaf(wgt, accp[(size_t)idx * 512 + g * 128 + d], osum);
  }
  attn[(size_t)b * HQ + kvh * 512 + g * 128 + d] = osum / lsum;
}

// ---------------------------------------------------------------------------
// DIAGNOSTIC PROBES — same byte set, three address patterns.
// Each wave's lane-0 result is stored so no load chain is dead.
// ---------------------------------------------------------------------------

// probe A: R6's pattern — per (b,kvh,chunk) block, 512B K slices at 4KB stride
// (32B/lane interleaved halves) + 512B V slices (8B/lane).
template <int REPS>
__global__ __launch_bounds__(256) void probe_gappy(const float* __restrict__ cache,
                                                   const int* __restrict__ seq_lens,
                                                   const int* __restrict__ slot_map,
                                                   const float* __restrict__ qkv,
                                                   float* __restrict__ sink) {
  const int t = threadIdx.x;
  const int bid = blockIdx.x;
  const int chunk = bid & 63;
  const int kvh = (bid >> 6) & 3;
  const int b = bid >> 8;
  const int L = seq_lens[b];
  const int start = chunk << 6;
  if (start >= L) return;
  const int n = min(CHUNK, L - start);
  const int send = start + n;
  const int slot = slot_map[b];
  const float* qrow = qkv + b * QKV_N;
  const float* knew = qrow + 2048 + (kvh << 7);
  const float* vnew = qrow + 2560 + (kvh << 7);
  const int w = t >> 6, l = t & 63;
  const int l16 = l & 15, rq = l >> 4;
  const int wbase = w << 4;

  auto krow_ptr = [&](int r) -> const float* {
    int sg = start + r;
    sg = (sg < send) ? sg : start;
    return (sg == slot) ? knew : cache + (((size_t)((b << 12) + sg)) << 10) + (kvh << 7);
  };
  auto vrow_ptr = [&](int r) -> const float* {
    int sg = start + r;
    sg = (sg < send) ? sg : start;
    return (sg == slot) ? vnew : cache + (((size_t)((b << 12) + sg)) << 10) + 512 + (kvh << 7);
  };

  float4 acc = make_float4(0.f, 0.f, 0.f, 0.f);
#pragma unroll 1
  for (int rep = 0; rep < REPS; ++rep) {
    asm volatile("" ::: "memory");
#pragma unroll
    for (int rg = 0; rg < 4; ++rg) {
      const float* kp = krow_ptr(wbase + (rg << 2) + rq) + (l16 << 3);
      const float4 a = *reinterpret_cast<const float4*>(kp);
      const float4 c = *reinterpret_cast<const float4*>(kp + 4);
      acc.x += a.x + c.x; acc.y += a.y + c.y; acc.z += a.z + c.z; acc.w += a.w + c.w;
    }
#pragma unroll
    for (int s = 0; s < 16; ++s) {
      const float2 v = *reinterpret_cast<const float2*>(vrow_ptr(wbase + s) + (l << 1));
      acc.x += v.x; acc.y += v.y;
    }
  }
  if (l == 0) sink[(bid << 2) + w] = acc.x + acc.y + acc.z + acc.w;
}

// probe B: same set, contiguous 16B/lane K requests (half the line requests).
template <int REPS>
__global__ __launch_bounds__(256) void probe_contig(const float* __restrict__ cache,
                                                    const int* __restrict__ seq_lens,
                                                    const int* __restrict__ slot_map,
                                                    const float* __restrict__ qkv,
                                                    float* __restrict__ sink) {
  const int t = threadIdx.x;
  const int bid = blockIdx.x;
  const int chunk = bid & 63;
  const int kvh = (bid >> 6) & 3;
  const int b = bid >> 8;
  const int L = seq_lens[b];
  const int start = chunk << 6;
  if (start >= L) return;
  const int n = min(CHUNK, L - start);
  const int send = start + n;
  const int slot = slot_map[b];
  const float* qrow = qkv + b * QKV_N;
  const float* knew = qrow + 2048 + (kvh << 7);
  const float* vnew = qrow + 2560 + (kvh << 7);
  const int w = t >> 6, l = t & 63;
  const int l16 = l & 15, rq = l >> 4;
  const int wbase = w << 4;

  auto krow_ptr = [&](int r) -> const float* {
    int sg = start + r;
    sg = (sg < send) ? sg : start;
    return (sg == slot) ? knew : cache + (((size_t)((b << 12) + sg)) << 10) + (kvh << 7);
  };
  auto vrow_ptr = [&](int r) -> const float* {
    int sg = start + r;
    sg = (sg < send) ? sg : start;
    return (sg == slot) ? vnew : cache + (((size_t)((b << 12) + sg)) << 10) + 512 + (kvh << 7);
  };

  float4 acc = make_float4(0.f, 0.f, 0.f, 0.f);
#pragma unroll 1
  for (int rep = 0; rep < REPS; ++rep) {
    asm volatile("" ::: "memory");
#pragma unroll
    for (int rg = 0; rg < 4; ++rg) {
      const float* kp = krow_ptr(wbase + (rg << 2) + rq) + (l16 << 2);
      const float4 a = *reinterpret_cast<const float4*>(kp);
      const float4 c = *reinterpret_cast<const float4*>(kp + 64);
      acc.x += a.x + c.x; acc.y += a.y + c.y; acc.z += a.z + c.z; acc.w += a.w + c.w;
    }
#pragma unroll
    for (int s = 0; s < 16; ++s) {
      const float2 v = *reinterpret_cast<const float2*>(vrow_ptr(wbase + s) + (l << 1));
      acc.x += v.x; acc.y += v.y;
    }
  }
  if (l == 0) sink[(bid << 2) + w] = acc.x + acc.y + acc.z + acc.w;
}

// probe C: identical bytes read as FULL contiguous 4KB (b,s) rows.
// grid 4096 = 32 b x 128 chunks of 32 rows; wave reads 8 whole rows (64B/lane).
template <int REPS>
__global__ __launch_bounds__(256) void probe_seq(const float* __restrict__ cache,
                                                 const int* __restrict__ seq_lens,
                                                 float* __restrict__ sink) {
  const int t = threadIdx.x;
  const int bid = blockIdx.x;
  const int chunk = bid & 127;
  const int b = bid >> 7;
  const int L = seq_lens[b];
  const int start = chunk << 5;
  if (start >= L) return;
  const int w = t >> 6, l = t & 63;

  float4 acc = make_float4(0.f, 0.f, 0.f, 0.f);
#pragma unroll 1
  for (int rep = 0; rep < REPS; ++rep) {
    asm volatile("" ::: "memory");
#pragma unroll
    for (int r = 0; r < 8; ++r) {
      int sg = start + (w << 3) + r;
      sg = (sg < L) ? sg : (L - 1);
      const float* p = cache + (((size_t)((b << 12) + sg)) << 10) + (l << 4);
      const float4 x0 = *reinterpret_cast<const float4*>(p);
      const float4 x1 = *reinterpret_cast<const float4*>(p + 4);
      const float4 x2 = *reinterpret_cast<const float4*>(p + 8);
      const float4 x3 = *reinterpret_cast<const float4*>(p + 12);
      acc.x += x0.x + x1.x + x2.x + x3.x;
      acc.y += x0.y + x1.y + x2.y + x3.y;
      acc.z += x0.z + x1.z + x2.z + x3.z;
      acc.w += x0.w + x1.w + x2.w + x3.w;
    }
  }
  if (l == 0) sink[(bid << 2) + w] = acc.x + acc.y + acc.z + acc.w;
}

// ---------------------------------------------------------------------------
extern "C" void kernel_launch(void* const* d_in, const int* in_sizes, int n_in,
                              void* d_out, int out_size, void* d_ws, size_t ws_size,
                              hipStream_t stream) {
  const float* hidden = (const float*)d_in[0];
  const float* cache = (const float*)d_in[2];
  const int* slot_map = (const int*)d_in[3];
  const int* seq_lens = (const int*)d_in[4];
  const float* Wqkv = (const float*)d_in[5];
  const float* bqkv = (const float*)d_in[6];
  const float* Wo = (const float*)d_in[7];
  float* out = (float*)d_out;
  float* ws = (float*)d_ws;

  float* qkv_part = ws;            // 16*32*3072 = 1,572,864
  float* qkv      = ws + 1572864;  // 98,304
  float* ml       = ws + 1671168;  // 8192*8 = 65,536
  float* accp     = ws + 1736704;  // 8192*512 = 4,194,304
  float* attn     = ws + 5931008;  // 65,536
  float* o_part   = ws + 5996544;  // 16*32*2048 = 1,048,576
  float* sinkA    = ws + 7045120;  // 32,768
  float* sinkB    = ws + 7077888;  // 32,768
  float* sinkC    = ws + 7110656;  // 16,384

  // real pipeline (R6 baseline)
  proj_kernel<QKV_N><<<dim3(48, KSPLIT), 256, 0, stream>>>(hidden, Wqkv, qkv_part);
  reduce_kernel<QKV_N, true><<<384, 256, 0, stream>>>(qkv_part, bqkv, qkv);
  attn_kernel<<<8192, 256, 0, stream>>>(cache, seq_lens, slot_map, qkv, ml, accp);
  combine_kernel<<<512, 128, 0, stream>>>(seq_lens, ml, accp, attn);
  proj_kernel<HQ><<<dim3(32, KSPLIT), 256, 0, stream>>>(attn, Wo, o_part);
  reduce_kernel<HQ, false><<<256, 256, 0, stream>>>(o_part, nullptr, out);

  // diagnostic probes (sacrificial timing round)
  probe_gappy<16><<<8192, 256, 0, stream>>>(cache, seq_lens, slot_map, qkv, sinkA);
  probe_contig<16><<<8192, 256, 0, stream>>>(cache, seq_lens, slot_map, qkv, sinkB);
  probe_seq<16><<<4096, 256, 0, stream>>>(cache, seq_lens, sinkC);
}

// Round 10
// 130.449 us; speedup vs baseline: 24.0124x; 24.0124x over previous
//
#include <hip/hip_runtime.h>
#include <cstddef>

#define HQ 2048
#define NKVH 4
#define HDIM 128
#define QKV_N 3072
#define ATT_SCALE 0.08838834764831845f
#define KSPLIT 16
#define CHUNK 64
#define NCH 64

__device__ __forceinline__ float4 f4max(float4 a, float4 b) {
  return make_float4(fmaxf(a.x, b.x), fmaxf(a.y, b.y), fmaxf(a.z, b.z), fmaxf(a.w, b.w));
}

// ---------------------------------------------------------------------------
// Projection: part[ksb][32][N] = X[32][2048] @ W[k-slice][N], K-split 16x128.
// grid (N/64, 16), block 256 = 64 cols x 4 ksub (32 K each).  [unchanged]
// ---------------------------------------------------------------------------
template <int N>
__global__ __launch_bounds__(256) void proj_kernel(const float* __restrict__ X,
                                                   const float* __restrict__ W,
                                                   float* __restrict__ part) {
  __shared__ union {
    float x[32][128];
    float red[32][4][64];
  } sm;
  const int t = threadIdx.x;
  const int c0 = blockIdx.x << 6;
  const int ksb = blockIdx.y;
  const int k0 = ksb << 7;
  const int c = t & 63;
  const int ksub = t >> 6;

#pragma unroll
  for (int i = 0; i < 4; ++i) {
    const int id = t + (i << 8);
    const int bb = id >> 5, kk = (id & 31) << 2;
    *reinterpret_cast<float4*>(&sm.x[bb][kk]) =
        *reinterpret_cast<const float4*>(X + bb * HQ + k0 + kk);
  }
  __syncthreads();

  float acc[32];
#pragma unroll
  for (int b = 0; b < 32; ++b) acc[b] = 0.f;

#pragma unroll
  for (int kk4 = 0; kk4 < 8; ++kk4) {
    const int kk = (ksub << 5) + (kk4 << 2);
    const float* wp = W + (size_t)(k0 + kk) * N + c0 + c;
    const float w0 = wp[0];
    const float w1 = wp[N];
    const float w2 = wp[2 * N];
    const float w3 = wp[3 * N];
#pragma unroll
    for (int b = 0; b < 32; ++b) {
      const float4 x4 = *reinterpret_cast<const float4*>(&sm.x[b][kk]);
      acc[b] = fmaf(x4.x, w0, acc[b]);
      acc[b] = fmaf(x4.y, w1, acc[b]);
      acc[b] = fmaf(x4.z, w2, acc[b]);
      acc[b] = fmaf(x4.w, w3, acc[b]);
    }
  }
  __syncthreads();
#pragma unroll
  for (int b = 0; b < 32; ++b) sm.red[b][ksub][c] = acc[b];
  __syncthreads();
#pragma unroll
  for (int i = 0; i < 8; ++i) {
    const int o = t + (i << 8);
    const int b = o >> 6, cc = o & 63;
    const float v = sm.red[b][0][cc] + sm.red[b][1][cc] + sm.red[b][2][cc] + sm.red[b][3][cc];
    part[(size_t)(ksb * 32 + b) * N + c0 + cc] = v;
  }
}

template <int NCOL, bool HAS_BIAS>
__global__ __launch_bounds__(256) void reduce_kernel(const float* __restrict__ part,
                                                     const float* __restrict__ bias,
                                                     float* __restrict__ out) {
  const int o = blockIdx.x * 256 + threadIdx.x;
  constexpr int total = 32 * NCOL;
  float s = 0.f;
#pragma unroll
  for (int ks = 0; ks < KSPLIT; ++ks) s += part[(size_t)ks * total + o];
  if (HAS_BIAS) s += bias[o % NCOL];
  out[o] = s;
}

// ---------------------------------------------------------------------------
// Flash-decode attention, CHUNK=64, 16 rows/wave — R6 structure +
// PER-BATCH CHUNK ROTATION for CU load balance: chunkEff = (chunk + 2b) & 63.
// Activity (chunkEff*64 < L) is a cyclic interval staggered per b, so every
// CU gets ~equal active blocks instead of low-chunk CUs doing all the work.
// Partials stored by chunkEff -> combine unchanged.
// ---------------------------------------------------------------------------
__global__ __launch_bounds__(256, 4) void attn_kernel(const float* __restrict__ cache,
                                                      const int* __restrict__ seq_lens,
                                                      const int* __restrict__ slot_map,
                                                      const float* __restrict__ qkv,
                                                      float* __restrict__ ml,
                                                      float* __restrict__ accp) {
  __shared__ float pt[4][16][4];
  __shared__ float pvbuf[4][128][4];
  __shared__ float redm[4][4];
  __shared__ float redl[4][4];

  const int t = threadIdx.x;
  const int bid = blockIdx.x;
  const int chunkRaw = bid & 63;
  const int kvh = (bid >> 6) & 3;
  const int b = bid >> 8;
  const int chunk = (chunkRaw + 2 * b) & 63;  // balance rotation
  const int L = seq_lens[b];
  const int start = chunk << 6;
  if (start >= L) return;
  const int n = min(CHUNK, L - start);
  const int send = start + n;
  const int slot = slot_map[b];
  const float* __restrict__ qrow = qkv + b * QKV_N;
  const float* __restrict__ knew = qrow + 2048 + (kvh << 7);
  const float* __restrict__ vnew = qrow + 2560 + (kvh << 7);
  const int oslot = (((b << 2) | kvh) << 6) + chunk;  // store by semantic chunk

  const int w = t >> 6, l = t & 63;
  const int l16 = l & 15, rq = l >> 4;
  const int wbase = w << 4;

  auto krow_ptr = [&](int r) -> const float* {
    int sg = start + r;
    sg = (sg < send) ? sg : start;
    return (sg == slot) ? knew : cache + (((size_t)((b << 12) + sg)) << 10) + (kvh << 7);
  };
  auto vrow_ptr = [&](int r) -> const float* {
    int sg = start + r;
    sg = (sg < send) ? sg : start;
    return (sg == slot) ? vnew : cache + (((size_t)((b << 12) + sg)) << 10) + 512 + (kvh << 7);
  };

  float4 qr[4][2];
#pragma unroll
  for (int g = 0; g < 4; ++g) {
#pragma unroll
    for (int e = 0; e < 2; ++e)
      qr[g][e] = *reinterpret_cast<const float4*>(qrow + ((kvh << 2) + g) * HDIM +
                                                  (l16 << 3) + (e << 2));
  }
  float4 ka[8];
#pragma unroll
  for (int rg = 0; rg < 4; ++rg) {
    const float* kp = krow_ptr(wbase + (rg << 2) + rq) + (l16 << 3);
    ka[2 * rg] = *reinterpret_cast<const float4*>(kp);
    ka[2 * rg + 1] = *reinterpret_cast<const float4*>(kp + 4);
  }
  float2 va[16];
#pragma unroll
  for (int s = 0; s < 16; ++s)
    va[s] = *reinterpret_cast<const float2*>(vrow_ptr(wbase + s) + (l << 1));

  float4 m4 = make_float4(-1e30f, -1e30f, -1e30f, -1e30f);
  float4 scr[4];
#pragma unroll
  for (int rg = 0; rg < 4; ++rg) {
    const float4 k0 = ka[2 * rg], k1 = ka[2 * rg + 1];
    float s0 = fmaf(k0.x, qr[0][0].x, fmaf(k0.y, qr[0][0].y, fmaf(k0.z, qr[0][0].z, k0.w * qr[0][0].w)));
    s0 = fmaf(k1.x, qr[0][1].x, fmaf(k1.y, qr[0][1].y, fmaf(k1.z, qr[0][1].z, fmaf(k1.w, qr[0][1].w, s0))));
    float s1 = fmaf(k0.x, qr[1][0].x, fmaf(k0.y, qr[1][0].y, fmaf(k0.z, qr[1][0].z, k0.w * qr[1][0].w)));
    s1 = fmaf(k1.x, qr[1][1].x, fmaf(k1.y, qr[1][1].y, fmaf(k1.z, qr[1][1].z, fmaf(k1.w, qr[1][1].w, s1))));
    float s2 = fmaf(k0.x, qr[2][0].x, fmaf(k0.y, qr[2][0].y, fmaf(k0.z, qr[2][0].z, k0.w * qr[2][0].w)));
    s2 = fmaf(k1.x, qr[2][1].x, fmaf(k1.y, qr[2][1].y, fmaf(k1.z, qr[2][1].z, fmaf(k1.w, qr[2][1].w, s2))));
    float s3 = fmaf(k0.x, qr[3][0].x, fmaf(k0.y, qr[3][0].y, fmaf(k0.z, qr[3][0].z, k0.w * qr[3][0].w)));
    s3 = fmaf(k1.x, qr[3][1].x, fmaf(k1.y, qr[3][1].y, fmaf(k1.z, qr[3][1].z, fmaf(k1.w, qr[3][1].w, s3))));
#pragma unroll
    for (int off = 1; off <= 8; off <<= 1) {
      s0 += __shfl_xor(s0, off);
      s1 += __shfl_xor(s1, off);
      s2 += __shfl_xor(s2, off);
      s3 += __shfl_xor(s3, off);
    }
    scr[rg] = make_float4(s0 * ATT_SCALE, s1 * ATT_SCALE, s2 * ATT_SCALE, s3 * ATT_SCALE);
    if (wbase + (rg << 2) + rq < n) m4 = f4max(m4, scr[rg]);
  }

  m4.x = fmaxf(m4.x, __shfl_xor(m4.x, 16));
  m4.y = fmaxf(m4.y, __shfl_xor(m4.y, 16));
  m4.z = fmaxf(m4.z, __shfl_xor(m4.z, 16));
  m4.w = fmaxf(m4.w, __shfl_xor(m4.w, 16));
  m4.x = fmaxf(m4.x, __shfl_xor(m4.x, 32));
  m4.y = fmaxf(m4.y, __shfl_xor(m4.y, 32));
  m4.z = fmaxf(m4.z, __shfl_xor(m4.z, 32));
  m4.w = fmaxf(m4.w, __shfl_xor(m4.w, 32));
  if (l == 0) *reinterpret_cast<float4*>(&redm[w][0]) = m4;
  __syncthreads();  // barrier A
  float4 M4 = *reinterpret_cast<const float4*>(&redm[0][0]);
  M4 = f4max(M4, *reinterpret_cast<const float4*>(&redm[1][0]));
  M4 = f4max(M4, *reinterpret_cast<const float4*>(&redm[2][0]));
  M4 = f4max(M4, *reinterpret_cast<const float4*>(&redm[3][0]));

  float4 lsum = make_float4(0.f, 0.f, 0.f, 0.f);
#pragma unroll
  for (int rg = 0; rg < 4; ++rg) {
    const int row = wbase + (rg << 2) + rq;
    float4 e = make_float4(0.f, 0.f, 0.f, 0.f);
    if (row < n) {
      e.x = __expf(scr[rg].x - M4.x);
      e.y = __expf(scr[rg].y - M4.y);
      e.z = __expf(scr[rg].z - M4.z);
      e.w = __expf(scr[rg].w - M4.w);
    }
    lsum.x += e.x; lsum.y += e.y; lsum.z += e.z; lsum.w += e.w;
    if (l16 == 0) *reinterpret_cast<float4*>(&pt[w][(rg << 2) + rq][0]) = e;
  }
  lsum.x += __shfl_xor(lsum.x, 16); lsum.y += __shfl_xor(lsum.y, 16);
  lsum.z += __shfl_xor(lsum.z, 16); lsum.w += __shfl_xor(lsum.w, 16);
  lsum.x += __shfl_xor(lsum.x, 32); lsum.y += __shfl_xor(lsum.y, 32);
  lsum.z += __shfl_xor(lsum.z, 32); lsum.w += __shfl_xor(lsum.w, 32);
  if (l == 0) *reinterpret_cast<float4*>(&redl[w][0]) = lsum;
  asm volatile("s_waitcnt lgkmcnt(0)" ::: "memory");  // wave-private pt fence

  float4 accA = make_float4(0.f, 0.f, 0.f, 0.f);
  float4 accB = make_float4(0.f, 0.f, 0.f, 0.f);
#pragma unroll
  for (int s = 0; s < 16; ++s) {
    const float4 p = *reinterpret_cast<const float4*>(&pt[w][s][0]);
    const float2 vv = va[s];
    accA.x = fmaf(p.x, vv.x, accA.x); accA.y = fmaf(p.y, vv.x, accA.y);
    accA.z = fmaf(p.z, vv.x, accA.z); accA.w = fmaf(p.w, vv.x, accA.w);
    accB.x = fmaf(p.x, vv.y, accB.x); accB.y = fmaf(p.y, vv.y, accB.y);
    accB.z = fmaf(p.z, vv.y, accB.z); accB.w = fmaf(p.w, vv.y, accB.w);
  }

  *reinterpret_cast<float4*>(&pvbuf[w][l << 1][0]) = accA;
  *reinterpret_cast<float4*>(&pvbuf[w][(l << 1) + 1][0]) = accB;
  __syncthreads();  // barrier B

  if (t < 128) {
    const int d = t;
    float4 s0 = *reinterpret_cast<const float4*>(&pvbuf[0][d][0]);
    const float4 s1 = *reinterpret_cast<const float4*>(&pvbuf[1][d][0]);
    const float4 s2 = *reinterpret_cast<const float4*>(&pvbuf[2][d][0]);
    const float4 s3 = *reinterpret_cast<const float4*>(&pvbuf[3][d][0]);
    s0.x += s1.x + s2.x + s3.x;
    s0.y += s1.y + s2.y + s3.y;
    s0.z += s1.z + s2.z + s3.z;
    s0.w += s1.w + s2.w + s3.w;
    float* ap = accp + (size_t)oslot * 512;
    ap[d] = s0.x;
    ap[128 + d] = s0.y;
    ap[256 + d] = s0.z;
    ap[384 + d] = s0.w;
  }
  if (t == 0) {
    float4 Lt = *reinterpret_cast<const float4*>(&redl[0][0]);
    const float4 l1 = *reinterpret_cast<const float4*>(&redl[1][0]);
    const float4 l2 = *reinterpret_cast<const float4*>(&redl[2][0]);
    const float4 l3 = *reinterpret_cast<const float4*>(&redl[3][0]);
    Lt.x += l1.x + l2.x + l3.x;
    Lt.y += l1.y + l2.y + l3.y;
    Lt.z += l1.z + l2.z + l3.z;
    Lt.w += l1.w + l2.w + l3.w;
    *reinterpret_cast<float4*>(ml + (size_t)oslot * 8) = M4;
    *reinterpret_cast<float4*>(ml + (size_t)oslot * 8 + 4) = Lt;
  }
}

// ---------------------------------------------------------------------------
// Combine chunk partials. grid 512 = (b,kvh,g), block 128 (d). [unchanged —
// attn stores by semantic chunk index]
// ---------------------------------------------------------------------------
__global__ __launch_bounds__(128) void combine_kernel(const int* __restrict__ seq_lens,
                                                      const float* __restrict__ ml,
                                                      const float* __restrict__ accp,
                                                      float* __restrict__ attn) {
  const int blk = blockIdx.x;
  const int g = blk & 3, kvh = (blk >> 2) & 3, b = blk >> 4;
  const int d = threadIdx.x;
  const int L = seq_lens[b];
  const int nch = (L + CHUNK - 1) >> 6;
  const int base = (b * 4 + kvh) * NCH;

  float M = -1e30f;
  for (int c = 0; c < nch; ++c) M = fmaxf(M, ml[(size_t)(base + c) * 8 + g]);
  float osum = 0.f, lsum = 0.f;
  for (int c = 0; c < nch; ++c) {
    const int idx = base + c;
    const float mc = ml[(size_t)idx * 8 + g];
    const float lc = ml[(size_t)idx * 8 + 4 + g];
    const float wgt = __expf(mc - M);
    lsum = fmaf(lc, wgt, lsum);
    osum = fmaf(wgt, accp[(size_t)idx * 512 + g * 128 + d], osum);
  }
  attn[(size_t)b * HQ + kvh * 512 + g * 128 + d] = osum / lsum;
}

// ---------------------------------------------------------------------------
extern "C" void kernel_launch(void* const* d_in, const int* in_sizes, int n_in,
                              void* d_out, int out_size, void* d_ws, size_t ws_size,
                              hipStream_t stream) {
  const float* hidden = (const float*)d_in[0];
  const float* cache = (const float*)d_in[2];
  const int* slot_map = (const int*)d_in[3];
  const int* seq_lens = (const int*)d_in[4];
  const float* Wqkv = (const float*)d_in[5];
  const float* bqkv = (const float*)d_in[6];
  const float* Wo = (const float*)d_in[7];
  float* out = (float*)d_out;
  float* ws = (float*)d_ws;

  float* qkv_part = ws;            // 16*32*3072 = 1,572,864
  float* qkv      = ws + 1572864;  // 98,304
  float* ml       = ws + 1671168;  // 8192*8 = 65,536
  float* accp     = ws + 1736704;  // 8192*512 = 4,194,304
  float* attn     = ws + 5931008;  // 65,536
  float* o_part   = ws + 5996544;  // 16*32*2048 = 1,048,576

  proj_kernel<QKV_N><<<dim3(48, KSPLIT), 256, 0, stream>>>(hidden, Wqkv, qkv_part);
  reduce_kernel<QKV_N, true><<<384, 256, 0, stream>>>(qkv_part, bqkv, qkv);
  attn_kernel<<<8192, 256, 0, stream>>>(cache, seq_lens, slot_map, qkv, ml, accp);
  combine_kernel<<<512, 128, 0, stream>>>(seq_lens, ml, accp, attn);
  proj_kernel<HQ><<<dim3(32, KSPLIT), 256, 0, stream>>>(attn, Wo, o_part);
  reduce_kernel<HQ, false><<<256, 256, 0, stream>>>(o_part, nullptr, out);
}